// Round 1
// baseline (565.142 us; speedup 1.0000x reference)
//
#include <hip/hip_runtime.h>

#define HH 512
#define WW 512
#define CIN 3
#define COUT 32
#define NB 16

typedef float f4 __attribute__((ext_vector_type(4)));

// Block: (64,4). Each thread: 4 consecutive x pixels, all 32 output channels.
// Grid: (2, 128, 16) -> x: 2*64*4=512, y: 128*4=512, z: batch.
__global__ __launch_bounds__(256)
void pointconv_kernel(const float* __restrict__ x,
                      const float* __restrict__ Wg,
                      const float* __restrict__ bias,
                      float* __restrict__ out) {
    // Effective 3x3 conv weights per o: 27 taps (c*9 + i*3 + j) + bias at [27].
    __shared__ float Wl[COUT * 28];

    const int tid = threadIdx.y * 64 + threadIdx.x;
    if (tid < COUT) {
        const int o = tid;
        // COORDS order -> tap index i*3+j within each channel's 3x3 block
        const int TAP[8] = {0, 3, 6, 1, 7, 2, 5, 8};
        float csum0 = 0.f, csum1 = 0.f, csum2 = 0.f;
        #pragma unroll
        for (int k = 0; k < 8; ++k) {
            float w0 = Wg[o * 24 + k * 3 + 0];
            float w1 = Wg[o * 24 + k * 3 + 1];
            float w2 = Wg[o * 24 + k * 3 + 2];
            Wl[o * 28 + 0 * 9 + TAP[k]] = w0;
            Wl[o * 28 + 1 * 9 + TAP[k]] = w1;
            Wl[o * 28 + 2 * 9 + TAP[k]] = w2;
            csum0 += w0; csum1 += w1; csum2 += w2;
        }
        Wl[o * 28 + 0 * 9 + 4] = -csum0;   // center tap = -sum(neighbor taps)
        Wl[o * 28 + 1 * 9 + 4] = -csum1;
        Wl[o * 28 + 2 * 9 + 4] = -csum2;
        Wl[o * 28 + 27] = bias[o];
    }
    __syncthreads();

    const int b  = blockIdx.z;
    const int y  = blockIdx.y * 4 + threadIdx.y;
    const int x0 = (blockIdx.x * 64 + threadIdx.x) * 4;

    // Stage 3 channels x 3 rows x 6 cols (x0-1 .. x0+4) into registers.
    float v[3][3][6];
    #pragma unroll
    for (int c = 0; c < 3; ++c) {
        const float* xc = x + ((size_t)(b * CIN + c) * HH) * WW;
        #pragma unroll
        for (int r = 0; r < 3; ++r) {
            const int yy = y + r - 1;
            const bool rowok = (yy >= 0) && (yy < HH);
            const float* row = xc + (ptrdiff_t)yy * WW;
            f4 mid;
            if (rowok) {
                mid = *(const f4*)(row + x0);
            } else {
                mid = (f4){0.f, 0.f, 0.f, 0.f};
            }
            v[c][r][1] = mid.x; v[c][r][2] = mid.y;
            v[c][r][3] = mid.z; v[c][r][4] = mid.w;
            v[c][r][0] = (rowok && x0 > 0)        ? row[x0 - 1] : 0.f;
            v[c][r][5] = (rowok && x0 + 4 < WW)   ? row[x0 + 4] : 0.f;
        }
    }

    float* outp = out + (((size_t)b * COUT) * HH + y) * WW + x0;

    #pragma unroll 1
    for (int o = 0; o < COUT; ++o) {
        const float* wo = &Wl[o * 28];
        const float bval = wo[27];
        float a0 = bval, a1 = bval, a2 = bval, a3 = bval;
        #pragma unroll
        for (int c = 0; c < 3; ++c) {
            #pragma unroll
            for (int t = 0; t < 9; ++t) {
                const int ty = t / 3, tx = t % 3;
                const float w = wo[c * 9 + t];
                a0 += w * v[c][ty][0 + tx];
                a1 += w * v[c][ty][1 + tx];
                a2 += w * v[c][ty][2 + tx];
                a3 += w * v[c][ty][3 + tx];
            }
        }
        f4 res = (f4){a0, a1, a2, a3};
        __builtin_nontemporal_store(res, (f4*)(outp + (size_t)o * (HH * WW)));
    }
}

extern "C" void kernel_launch(void* const* d_in, const int* in_sizes, int n_in,
                              void* d_out, int out_size, void* d_ws, size_t ws_size,
                              hipStream_t stream) {
    const float* x    = (const float*)d_in[0];
    const float* Wg   = (const float*)d_in[1];
    const float* bias = (const float*)d_in[2];
    float* out = (float*)d_out;

    dim3 block(64, 4, 1);
    dim3 grid(2, 128, 16);
    hipLaunchKernelGGL(pointconv_kernel, grid, block, 0, stream, x, Wg, bias, out);
}